// Round 3
// baseline (375.342 us; speedup 1.0000x reference)
//
#include <hip/hip_runtime.h>
#include <hip/hip_cooperative_groups.h>
#include <math.h>

namespace cg = cooperative_groups;

// Problem constants (fixed by reference setup_inputs)
constexpr int Nn = 2, Hh = 8, Ll = 2048, Dd = 64;
constexpr int S  = Nn * Hh;      // 16 sequences
constexpr int C  = 64;           // chunk length
constexpr int NC = Ll / C;       // 32 chunks/seq
constexpr int SC = S * NC;       // 512 chunk-blocks

constexpr int SRT = 68;          // stride for transposed operand tiles (16B-aligned rows)
constexpr int SRP = 65;          // stride for score matrix P (scalar scans conflict-free)

#define EPSF 1e-6f

__device__ __forceinline__ float sigf(float x) { return 1.0f / (1.0f + expf(-x)); }

__device__ __forceinline__ float waveRed(float v) {
#pragma unroll
    for (int off = 32; off > 0; off >>= 1) v += __shfl_xor(v, off, 64);
    return v;
}

__device__ __forceinline__ int gidx(int n, int l, int h, int d) {
    return ((n * Ll + l) * Hh + h) * Dd + d;
}

__device__ __forceinline__ float fc(const float4& v, int u) { return ((const float*)&v)[u]; }

// One cooperative kernel. grid=512 blocks (one per chunk), block=256.
// 2 blocks/CU co-resident (LDS ~54KB/block, launch_bounds(256,2)).
__global__ __launch_bounds__(256, 2) void k_fused(
        const float* __restrict__ Q, const float* __restrict__ K,
        const float* __restrict__ V, float* __restrict__ Out,
        float* __restrict__ SK, float* __restrict__ SQ,
        float* __restrict__ SKso, float* __restrict__ SQsi,
        float* __restrict__ Tcs, float* __restrict__ KV) {
    cg::grid_group grid = cg::this_grid();

    __shared__ float sqT[Dd * SRT];   // sigmoid(q) transposed [d][i]; reused for masked S^T in P8
    __shared__ float skb[Dd * SRT];   // sigmoid(k) transposed [d][i]; reused for KV-prefix in P8
    __shared__ float P[C * SRP];      // scores P[i][j] (first 2KB doubles as staging scratch)
    __shared__ float colK[C], colQ[C], pk[Dd], pq[Dd];
    __shared__ float lsi[C], lso[C], le[C], lecum[C], s2[C], lsc[C];
    __shared__ float pcsv;

    int b = blockIdx.x, s = b / NC, c = b % NC;
    int n = s / Hh, h = s % Hh, t = threadIdx.x;
    int tx = t & 15, ty = t >> 4;
    int i0 = 4 * ty, j0 = 4 * tx;     // ty in 0..15 (only 0..3 within a wave -> conflict-free tiles)

    // ---------------- P0: stage + chunk sums + score matrix ----------------
    float psk[4] = {0, 0, 0, 0}, psq[4] = {0, 0, 0, 0};
    int d0 = (4 * t) & 63, ig = t >> 4;
#pragma unroll
    for (int j = 0; j < 4; j++) {
        int i = ig + 16 * j;
        int id = gidx(n, c * C + i, h, d0);
        float4 q4 = *(const float4*)&Q[id];
        float4 k4 = *(const float4*)&K[id];
        float sq0 = sigf(q4.x), sq1 = sigf(q4.y), sq2 = sigf(q4.z), sq3 = sigf(q4.w);
        float sk0 = sigf(k4.x), sk1 = sigf(k4.y), sk2 = sigf(k4.z), sk3 = sigf(k4.w);
        sqT[(d0 + 0) * SRT + i] = sq0; sqT[(d0 + 1) * SRT + i] = sq1;
        sqT[(d0 + 2) * SRT + i] = sq2; sqT[(d0 + 3) * SRT + i] = sq3;
        skb[(d0 + 0) * SRT + i] = sk0; skb[(d0 + 1) * SRT + i] = sk1;
        skb[(d0 + 2) * SRT + i] = sk2; skb[(d0 + 3) * SRT + i] = sk3;
        psq[0] += sq0; psq[1] += sq1; psq[2] += sq2; psq[3] += sq3;
        psk[0] += sk0; psk[1] += sk1; psk[2] += sk2; psk[3] += sk3;
    }
    // register partial sums -> scratch (low 2KB of P)
    float* scrK = P;
    float* scrQ = P + 1024;
#pragma unroll
    for (int r = 0; r < 4; r++) {
        scrK[ig * 64 + d0 + r] = psk[r];
        scrQ[ig * 64 + d0 + r] = psq[r];
    }
    __syncthreads();
    if (t < 64) {
        float v = 0.f;
        for (int g = 0; g < 16; g++) v += scrK[g * 64 + t];
        SK[b * 64 + t] = v;
    } else if (t < 128) {
        int d = t - 64; float v = 0.f;
        for (int g = 0; g < 16; g++) v += scrQ[g * 64 + d];
        SQ[b * 64 + d] = v;
    } else if (t < 192) {
        int i = t - 128; float v = 0.f;
        for (int d = 0; d < Dd; d++) v += skb[d * SRT + i];
        colK[i] = v;
    } else {
        int i = t - 192; float v = 0.f;
        for (int d = 0; d < Dd; d++) v += sqT[d * SRT + i];
        colQ[i] = v;
    }
    __syncthreads();
    {   // P[i][j] = sum_d sq_i[d]*sk_j[d]
        float acc[4][4] = {};
        for (int d = 0; d < Dd; d++) {
            float4 a = *(const float4*)&sqT[d * SRT + i0];
            float4 bb = *(const float4*)&skb[d * SRT + j0];
#pragma unroll
            for (int r = 0; r < 4; r++)
#pragma unroll
                for (int cc = 0; cc < 4; cc++) acc[r][cc] += fc(a, r) * fc(bb, cc);
        }
#pragma unroll
        for (int r = 0; r < 4; r++)
#pragma unroll
            for (int cc = 0; cc < 4; cc++) P[(i0 + r) * SRP + (j0 + cc)] = acc[r][cc];
    }

    grid.sync();   // ---- sync 1: SK/SQ visible ----

    // ---------------- P2': si/so + SKso/SQsi ----------------
    if (t < 64) {
        float v = 0.f;
        for (int cp = 0; cp < c; cp++) v += SK[(s * NC + cp) * 64 + t];
        pk[t] = v;
    } else if (t < 128) {
        int d = t - 64; float v = 0.f;
        for (int cp = 0; cp < c; cp++) v += SQ[(s * NC + cp) * 64 + d];
        pq[d] = v;
    }
    __syncthreads();
    if (t < 64) {
        int i = t, l = c * C + i;
        float r1 = 0.f, r2 = 0.f;
        for (int j = 0; j <= i; j++) {
            r1 += P[i * SRP + j] + EPSF * colK[j];
            r2 += P[j * SRP + i] + EPSF * colQ[j];
        }
        float b1 = 0.f, b2 = 0.f;
        for (int d = 0; d < Dd; d++) {
            b1 += (sqT[d * SRT + i] + EPSF) * (pk[d] + EPSF);
            b2 += (skb[d * SRT + i] + EPSF) * (pq[d] + EPSF);
        }
        float nf = (float)(l + 1);
        lsi[i] = nf / (b1 + r1);
        lso[i] = nf / (b2 + r2);
    }
    __syncthreads();
    if (t < 64) {
        float v = 0.f;
        for (int i = 0; i < C; i++) v += skb[t * SRT + i] * lso[i];
        SKso[b * 64 + t] = v;
    } else if (t < 128) {
        int d = t - 64; float v = 0.f;
        for (int i = 0; i < C; i++) v += sqT[d * SRT + i] * lsi[i];
        SQsi[b * 64 + d] = v;
    }

    grid.sync();   // ---- sync 2: SKso/SQsi visible ----

    // ---------------- P4': sal, e, chunk-local cumsum, Tcs ----------------
    if (t < 64) {
        float v = 0.f;
        for (int cp = 0; cp < c; cp++) v += SKso[(s * NC + cp) * 64 + t];
        pk[t] = v;   // reuse as pks
    } else if (t < 128) {
        int d = t - 64; float v = 0.f;
        for (int cp = 0; cp < c; cp++) v += SQsi[(s * NC + cp) * 64 + d];
        pq[d] = v;   // reuse as pqs
    }
    __syncthreads();
    if (t < 64) {
        int i = t, l = c * C + i;
        float rw1 = 0.f, rw2 = 0.f;
        for (int j = 0; j <= i; j++) {
            rw1 += lso[j] * (P[i * SRP + j] + EPSF * colK[j]);
            rw2 += lsi[j] * (P[j * SRP + i] + EPSF * colQ[j]);
        }
        float b1 = 0.f, b2 = 0.f;
        for (int d = 0; d < Dd; d++) {
            b1 += (sqT[d * SRT + i] + EPSF) * (pk[d] + EPSF);
            b2 += (skb[d * SRT + i] + EPSF) * (pq[d] + EPSF);
        }
        float nf = (float)(l + 1);
        float cs = (b1 + rw1) / nf;
        float csr = (b2 + rw2) / nf;
        csr = fminf(fmaxf(csr, -1.f), 1.f);
        float e = expf(csr);
        float sal = 1.0f / (1.0f + expf(-cs));
        s2[i] = lsi[i] / nf * sal;
        le[i] = e;
        float run = e;
#pragma unroll
        for (int off = 1; off < 64; off <<= 1) {
            float o = __shfl_up(run, off, 64);
            if (i >= off) run += o;
        }
        lecum[i] = run;
        if (i == 63) Tcs[b] = run;
    }

    grid.sync();   // ---- sync 3: Tcs visible ----

    // ---------------- P6': scomp + chunk KV ----------------
    if (t < 64) {
        float v = (t < c) ? Tcs[s * NC + t] : 0.f;
        v = waveRed(v);
        if (t == 0) pcsv = v;
    }
    __syncthreads();
    if (t < 64) lsc[t] = le[t] / (pcsv + lecum[t]) * (float)(c * C + t + 1);
    __syncthreads();
    {   // KV_c[d][m] = sum_i sk_i[d] * (v_i[m]*scomp_i); tile d=i0.., m=j0..
        float acc[4][4] = {};
        for (int ii = 0; ii < C; ii += 4) {
            float4 kk[4], vv[4];
#pragma unroll
            for (int r = 0; r < 4; r++) kk[r] = *(const float4*)&skb[(i0 + r) * SRT + ii];
#pragma unroll
            for (int u = 0; u < 4; u++) {
                float4 v4 = *(const float4*)&V[gidx(n, c * C + ii + u, h, j0)];
                float ls = lsc[ii + u];
                vv[u] = make_float4(v4.x * ls, v4.y * ls, v4.z * ls, v4.w * ls);
            }
#pragma unroll
            for (int u = 0; u < 4; u++)
#pragma unroll
                for (int r = 0; r < 4; r++)
#pragma unroll
                    for (int cc = 0; cc < 4; cc++)
                        acc[r][cc] += fc(kk[r], u) * fc(vv[u], cc);
        }
        float* dst = &KV[(size_t)b * (Dd * Dd)];
#pragma unroll
        for (int r = 0; r < 4; r++) {
            float4 o = {acc[r][0], acc[r][1], acc[r][2], acc[r][3]};
            *(float4*)&dst[(i0 + r) * Dd + j0] = o;
        }
    }

    grid.sync();   // ---- sync 4: all chunk KVs written ----

    // ---------------- P7: exclusive chunk-prefix of KV (256 blocks) ----------------
    if (b < 256) {
        int sg = b >> 4, sub = b & 15;
        int e0 = sub * 256 + t;
        float x[NC];
#pragma unroll
        for (int cp = 0; cp < NC; cp++)
            x[cp] = KV[(size_t)(sg * NC + cp) * (Dd * Dd) + e0];
        float r = 0.f;
#pragma unroll
        for (int cp = 0; cp < NC; cp++) {
            float tv = x[cp];
            KV[(size_t)(sg * NC + cp) * (Dd * Dd) + e0] = r;
            r += tv;
        }
    }

    grid.sync();   // ---- sync 5: KV prefixes ready ----

    // ---------------- P8: out = s2 * (sq . KVp  +  maskedP.scomp.v) ----------------
#pragma unroll
    for (int j = 0; j < 4; j++) {   // stage KVp into skb (stride SRT)
        int flat = 4 * t + 1024 * j, dq = flat >> 6, mm = flat & 63;
        float4 kv4 = *(const float4*)&KV[(size_t)b * (Dd * Dd) + dq * 64 + mm];
        *(float4*)&skb[dq * SRT + mm] = kv4;
    }
    __syncthreads();
    float acc[4][4] = {};
    for (int d = 0; d < Dd; d++) {   // matmul1: sq^T x KVp
        float4 a = *(const float4*)&sqT[d * SRT + i0];
        float4 bb = *(const float4*)&skb[d * SRT + j0];
#pragma unroll
        for (int r = 0; r < 4; r++)
#pragma unroll
            for (int cc = 0; cc < 4; cc++) acc[r][cc] += fc(a, r) * fc(bb, cc);
    }
    __syncthreads();   // done reading sqT
#pragma unroll
    for (int cc = 0; cc < 4; cc++) {   // masked S^T (scomp folded) -> sqT
        int j = j0 + cc;
        float lj = lsc[j];
        float4 v;
        v.x = (j <= i0 + 0) ? P[(i0 + 0) * SRP + j] * lj : 0.f;
        v.y = (j <= i0 + 1) ? P[(i0 + 1) * SRP + j] * lj : 0.f;
        v.z = (j <= i0 + 2) ? P[(i0 + 2) * SRP + j] * lj : 0.f;
        v.w = (j <= i0 + 3) ? P[(i0 + 3) * SRP + j] * lj : 0.f;
        *(float4*)&sqT[j * SRT + i0] = v;
    }
    __syncthreads();
    for (int j = 0; j < C; j++) {   // matmul2: ST^T x v (v from global, L1-hot)
        float4 a = *(const float4*)&sqT[j * SRT + i0];
        float4 bb = *(const float4*)&V[gidx(n, c * C + j, h, j0)];
#pragma unroll
        for (int r = 0; r < 4; r++)
#pragma unroll
            for (int cc = 0; cc < 4; cc++) acc[r][cc] += fc(a, r) * fc(bb, cc);
    }
#pragma unroll
    for (int r = 0; r < 4; r++) {
        float sf = s2[i0 + r];
        float4 o = {acc[r][0] * sf, acc[r][1] * sf, acc[r][2] * sf, acc[r][3] * sf};
        *(float4*)&Out[gidx(n, c * C + i0 + r, h, j0)] = o;
    }
}

extern "C" void kernel_launch(void* const* d_in, const int* in_sizes, int n_in,
                              void* d_out, int out_size, void* d_ws, size_t ws_size,
                              hipStream_t stream) {
    const float* Q = (const float*)d_in[0];
    const float* K = (const float*)d_in[1];
    const float* V = (const float*)d_in[2];
    float* Out = (float*)d_out;

    float* ws    = (float*)d_ws;
    float* pSK   = ws;                  // SC*64
    float* pSQ   = pSK   + SC * Dd;
    float* pSKso = pSQ   + SC * Dd;
    float* pSQsi = pSKso + SC * Dd;
    float* pTcs  = pSQsi + SC * Dd;     // SC
    float* pKV   = pTcs  + SC;          // SC*4096 (~8.4 MB)

    void* args[] = {(void*)&Q, (void*)&K, (void*)&V, (void*)&Out,
                    (void*)&pSK, (void*)&pSQ, (void*)&pSKso, (void*)&pSQsi,
                    (void*)&pTcs, (void*)&pKV};
    hipLaunchCooperativeKernel((const void*)k_fused, dim3(SC), dim3(256), args, 0, stream);
}

// Round 4
// 139.847 us; speedup vs baseline: 2.6840x; 2.6840x over previous
//
#include <hip/hip_runtime.h>
#include <math.h>

// Problem constants (fixed by reference setup_inputs)
constexpr int Nn = 2, Hh = 8, Ll = 2048, Dd = 64;
constexpr int S  = Nn * Hh;      // 16 sequences
constexpr int C  = 64;           // chunk length
constexpr int NC = Ll / C;       // 32 chunks/seq
constexpr int SC = S * NC;       // 512 chunk-blocks

constexpr int SRT = 68;          // stride for transposed operand tiles (16B-aligned rows)
constexpr int SRP = 65;          // stride for score matrix P (scalar scans ~conflict-free)

#define EPSF 1e-6f

__device__ __forceinline__ float sigf(float x) { return 1.0f / (1.0f + expf(-x)); }

__device__ __forceinline__ float waveRed(float v) {
#pragma unroll
    for (int off = 32; off > 0; off >>= 1) v += __shfl_xor(v, off, 64);
    return v;
}

__device__ __forceinline__ int gidx(int n, int l, int h, int d) {
    return ((n * Ll + l) * Hh + h) * Dd + d;
}

__device__ __forceinline__ float fc(const float4& v, int u) { return ((const float*)&v)[u]; }

// K1: per-chunk sums of sigmoid(k), sigmoid(q). 256 threads/chunk for latency hiding.
__global__ __launch_bounds__(256) void k_sums(const float* __restrict__ Q,
                                              const float* __restrict__ K,
                                              float* __restrict__ SK, float* __restrict__ SQ) {
    __shared__ float scr[2048];
    int b = blockIdx.x, s = b / NC, c = b % NC;
    int n = s / Hh, h = s % Hh, t = threadIdx.x;
    int d0 = (4 * t) & 63, ig = t >> 4;
    float psk[4] = {0, 0, 0, 0}, psq[4] = {0, 0, 0, 0};
#pragma unroll
    for (int j = 0; j < 4; j++) {
        int i = ig + 16 * j;
        int id = gidx(n, c * C + i, h, d0);
        float4 q4 = *(const float4*)&Q[id];
        float4 k4 = *(const float4*)&K[id];
        psq[0] += sigf(q4.x); psq[1] += sigf(q4.y); psq[2] += sigf(q4.z); psq[3] += sigf(q4.w);
        psk[0] += sigf(k4.x); psk[1] += sigf(k4.y); psk[2] += sigf(k4.z); psk[3] += sigf(k4.w);
    }
#pragma unroll
    for (int r = 0; r < 4; r++) {
        scr[ig * 64 + d0 + r] = psk[r];
        scr[1024 + ig * 64 + d0 + r] = psq[r];
    }
    __syncthreads();
    if (t < 64) {
        float v = 0.f;
        for (int g = 0; g < 16; g++) v += scr[g * 64 + t];
        SK[b * 64 + t] = v;
    } else if (t < 128) {
        int d = t - 64; float v = 0.f;
        for (int g = 0; g < 16; g++) v += scr[1024 + g * 64 + d];
        SQ[b * 64 + d] = v;
    }
}

// K2: pass1 — stage, P matmul (stored to Pg), si/so, SKso/SQsi chunk sums.
__global__ __launch_bounds__(256) void k_pass1(const float* __restrict__ Q,
                                               const float* __restrict__ K,
                                               const float* __restrict__ SK,
                                               const float* __restrict__ SQ,
                                               float* __restrict__ SKso,
                                               float* __restrict__ SQsi,
                                               float* __restrict__ si_g,
                                               float* __restrict__ so_g,
                                               float* __restrict__ Pg) {
    __shared__ float sqT[Dd * SRT];
    __shared__ float skT[Dd * SRT];
    __shared__ float P[C * SRP];
    __shared__ float colK[C], colQ[C], pk[Dd], pq[Dd], lsi[C], lso[C];
    int b = blockIdx.x, s = b / NC, c = b % NC;
    int n = s / Hh, h = s % Hh, t = threadIdx.x;
    int tx = t & 15, ty = t >> 4, i0 = 4 * ty, j0 = 4 * tx;

#pragma unroll
    for (int j = 0; j < 4; j++) {
        int flat = 4 * t + 1024 * j, i = flat >> 6, d0 = flat & 63;
        int id = gidx(n, c * C + i, h, d0);
        float4 q4 = *(const float4*)&Q[id];
        float4 k4 = *(const float4*)&K[id];
        sqT[(d0 + 0) * SRT + i] = sigf(q4.x);
        sqT[(d0 + 1) * SRT + i] = sigf(q4.y);
        sqT[(d0 + 2) * SRT + i] = sigf(q4.z);
        sqT[(d0 + 3) * SRT + i] = sigf(q4.w);
        skT[(d0 + 0) * SRT + i] = sigf(k4.x);
        skT[(d0 + 1) * SRT + i] = sigf(k4.y);
        skT[(d0 + 2) * SRT + i] = sigf(k4.z);
        skT[(d0 + 3) * SRT + i] = sigf(k4.w);
    }
    __syncthreads();

    if (t < 64) {
        float v = 0.f;
        for (int d = 0; d < Dd; d++) v += skT[d * SRT + t];
        colK[t] = v;
    } else if (t < 128) {
        int i = t - 64; float v = 0.f;
        for (int d = 0; d < Dd; d++) v += sqT[d * SRT + i];
        colQ[i] = v;
    } else if (t < 192) {
        int d = t - 128; float v = 0.f;
        for (int cp = 0; cp < c; cp++) v += SK[(s * NC + cp) * 64 + d];
        pk[d] = v;
    } else {
        int d = t - 192; float v = 0.f;
        for (int cp = 0; cp < c; cp++) v += SQ[(s * NC + cp) * 64 + d];
        pq[d] = v;
    }

    // P matmul (no sync needed before: tiles read only sqT/skT, synced above)
    float acc[4][4] = {};
    for (int d = 0; d < Dd; d++) {
        float4 a = *(const float4*)&sqT[d * SRT + i0];
        float4 bb = *(const float4*)&skT[d * SRT + j0];
#pragma unroll
        for (int r = 0; r < 4; r++)
#pragma unroll
            for (int cc = 0; cc < 4; cc++) acc[r][cc] += fc(a, r) * fc(bb, cc);
    }
#pragma unroll
    for (int r = 0; r < 4; r++) {
#pragma unroll
        for (int cc = 0; cc < 4; cc++) P[(i0 + r) * SRP + (j0 + cc)] = acc[r][cc];
        float4 o = {acc[r][0], acc[r][1], acc[r][2], acc[r][3]};
        *(float4*)&Pg[(size_t)b * 4096 + (i0 + r) * 64 + j0] = o;
    }
    __syncthreads();

    if (t < 64) {
        int i = t, l = c * C + i;
        float r1 = 0.f, r2 = 0.f;
        for (int j = 0; j <= i; j++) {
            r1 += P[i * SRP + j] + EPSF * colK[j];
            r2 += P[j * SRP + i] + EPSF * colQ[j];
        }
        float b1 = 0.f, b2 = 0.f;
        for (int d = 0; d < Dd; d++) {
            b1 += (sqT[d * SRT + i] + EPSF) * (pk[d] + EPSF);
            b2 += (skT[d * SRT + i] + EPSF) * (pq[d] + EPSF);
        }
        float nf = (float)(l + 1);
        float siF = nf / (b1 + r1), soF = nf / (b2 + r2);
        si_g[s * Ll + l] = siF; so_g[s * Ll + l] = soF;
        lsi[i] = siF; lso[i] = soF;
    }
    __syncthreads();

    if (t < 64) {
        float v = 0.f;
        for (int i = 0; i < C; i++) v += skT[t * SRT + i] * lso[i];
        SKso[b * 64 + t] = v;
    } else if (t < 128) {
        int d = t - 64; float v = 0.f;
        for (int i = 0; i < C; i++) v += sqT[d * SRT + i] * lsi[i];
        SQsi[b * 64 + d] = v;
    }
}

// K3: pass2 — NO matmul (reloads Pg). Emits s2, e, ecum, Tcs.
__global__ __launch_bounds__(256) void k_pass2(const float* __restrict__ Q,
                                               const float* __restrict__ K,
                                               const float* __restrict__ SKso,
                                               const float* __restrict__ SQsi,
                                               const float* __restrict__ si_g,
                                               const float* __restrict__ so_g,
                                               const float* __restrict__ Pg,
                                               float* __restrict__ s2_g,
                                               float* __restrict__ e_g,
                                               float* __restrict__ ecum_g,
                                               float* __restrict__ Tcs) {
    __shared__ float sqT[Dd * SRT];
    __shared__ float skT[Dd * SRT];
    __shared__ float P[C * SRP];
    __shared__ float colK[C], colQ[C], pks[Dd], pqs[Dd], lsi[C], lso[C];
    int b = blockIdx.x, s = b / NC, c = b % NC;
    int n = s / Hh, h = s % Hh, t = threadIdx.x;

    if (t < 64) lsi[t] = si_g[s * Ll + c * C + t];
    else if (t < 128) lso[t - 64] = so_g[s * Ll + c * C + (t - 64)];

#pragma unroll
    for (int j = 0; j < 4; j++) {
        int flat = 4 * t + 1024 * j, i = flat >> 6, d0 = flat & 63;
        int id = gidx(n, c * C + i, h, d0);
        float4 q4 = *(const float4*)&Q[id];
        float4 k4 = *(const float4*)&K[id];
        float4 p4 = *(const float4*)&Pg[(size_t)b * 4096 + flat];
        sqT[(d0 + 0) * SRT + i] = sigf(q4.x);
        sqT[(d0 + 1) * SRT + i] = sigf(q4.y);
        sqT[(d0 + 2) * SRT + i] = sigf(q4.z);
        sqT[(d0 + 3) * SRT + i] = sigf(q4.w);
        skT[(d0 + 0) * SRT + i] = sigf(k4.x);
        skT[(d0 + 1) * SRT + i] = sigf(k4.y);
        skT[(d0 + 2) * SRT + i] = sigf(k4.z);
        skT[(d0 + 3) * SRT + i] = sigf(k4.w);
        P[i * SRP + d0 + 0] = p4.x;
        P[i * SRP + d0 + 1] = p4.y;
        P[i * SRP + d0 + 2] = p4.z;
        P[i * SRP + d0 + 3] = p4.w;
    }
    __syncthreads();

    if (t < 64) {
        float v = 0.f;
        for (int d = 0; d < Dd; d++) v += skT[d * SRT + t];
        colK[t] = v;
    } else if (t < 128) {
        int i = t - 64; float v = 0.f;
        for (int d = 0; d < Dd; d++) v += sqT[d * SRT + i];
        colQ[i] = v;
    } else if (t < 192) {
        int d = t - 128; float v = 0.f;
        for (int cp = 0; cp < c; cp++) v += SKso[(s * NC + cp) * 64 + d];
        pks[d] = v;
    } else {
        int d = t - 192; float v = 0.f;
        for (int cp = 0; cp < c; cp++) v += SQsi[(s * NC + cp) * 64 + d];
        pqs[d] = v;
    }
    __syncthreads();

    if (t < 64) {
        int i = t, l = c * C + i;
        float rw1 = 0.f, rw2 = 0.f;
        for (int j = 0; j <= i; j++) {
            rw1 += lso[j] * (P[i * SRP + j] + EPSF * colK[j]);
            rw2 += lsi[j] * (P[j * SRP + i] + EPSF * colQ[j]);
        }
        float b1 = 0.f, b2 = 0.f;
        for (int d = 0; d < Dd; d++) {
            b1 += (sqT[d * SRT + i] + EPSF) * (pks[d] + EPSF);
            b2 += (skT[d * SRT + i] + EPSF) * (pqs[d] + EPSF);
        }
        float nf = (float)(l + 1);
        float cs  = (b1 + rw1) / nf;
        float csr = (b2 + rw2) / nf;
        csr = fminf(fmaxf(csr, -1.f), 1.f);
        float e = expf(csr);
        float sal = 1.0f / (1.0f + expf(-cs));
        s2_g[s * Ll + l] = lsi[i] / nf * sal;
        e_g[s * Ll + l] = e;
        float run = e;
#pragma unroll
        for (int off = 1; off < 64; off <<= 1) {
            float o = __shfl_up(run, off, 64);
            if (i >= off) run += o;
        }
        ecum_g[s * Ll + l] = run;
        if (i == 63) Tcs[b] = run;
    }
}

// K4: scomp (inline Tcs prefix) + chunk KV matmul.
__global__ __launch_bounds__(256) void k_kv(const float* __restrict__ K,
                                            const float* __restrict__ V,
                                            const float* __restrict__ e_g,
                                            const float* __restrict__ ecum_g,
                                            const float* __restrict__ Tcs,
                                            float* __restrict__ scomp_g,
                                            float* __restrict__ KV) {
    __shared__ float lk[C][Dd];
    __shared__ float lvs[C][Dd];
    __shared__ float lsc[C];
    __shared__ float pcsv;
    int b = blockIdx.x, s = b / NC, c = b % NC;
    int n = s / Hh, h = s % Hh, t = threadIdx.x;
    if (t < 64) {
        float v = (t < c) ? Tcs[s * NC + t] : 0.f;
        v = waveRed(v);
        if (t == 0) pcsv = v;
    }
    __syncthreads();
    if (t < 64) {
        int l = c * C + t;
        float ls = e_g[s * Ll + l] / (pcsv + ecum_g[s * Ll + l]) * (float)(l + 1);
        lsc[t] = ls;
        scomp_g[s * Ll + l] = ls;
    }
    __syncthreads();
#pragma unroll
    for (int j = 0; j < 16; j++) {
        int flat = t + 256 * j, i = flat >> 6, d = flat & 63;
        int id = gidx(n, c * C + i, h, d);
        lk[i][d]  = sigf(K[id]);
        lvs[i][d] = V[id] * lsc[i];
    }
    __syncthreads();
    int tx = t & 15, ty = t >> 4, m0 = tx * 4, d0 = ty * 4;
    float acc[4][4] = {};
    for (int i = 0; i < C; i++) {
        float4 k4 = *(const float4*)&lk[i][d0];
        float4 v4 = *(const float4*)&lvs[i][m0];
#pragma unroll
        for (int r = 0; r < 4; r++)
#pragma unroll
            for (int cc = 0; cc < 4; cc++) acc[r][cc] += fc(k4, r) * fc(v4, cc);
    }
    float* dst = &KV[(size_t)b * 4096];
#pragma unroll
    for (int r = 0; r < 4; r++) {
        float4 o = {acc[r][0], acc[r][1], acc[r][2], acc[r][3]};
        *(float4*)&dst[(d0 + r) * 64 + m0] = o;
    }
}

// K5: exclusive chunk-prefix of KV (register-preload). grid=256.
__global__ __launch_bounds__(256) void k_prefixKV(float* __restrict__ KV) {
    int bx = blockIdx.x, s = bx >> 4, sub = bx & 15;
    int e0 = sub * 256 + threadIdx.x;
    float x[NC];
#pragma unroll
    for (int cp = 0; cp < NC; cp++)
        x[cp] = KV[(size_t)(s * NC + cp) * 4096 + e0];
    float r = 0.f;
#pragma unroll
    for (int cp = 0; cp < NC; cp++) {
        float tv = x[cp];
        KV[(size_t)(s * NC + cp) * 4096 + e0] = r;
        r += tv;
    }
}

// K6: final — out = s2 * (sq·KVp + maskedP·scomp·v). No K staging, P from Pg.
__global__ __launch_bounds__(256) void k_final(const float* __restrict__ Q,
                                               const float* __restrict__ V,
                                               const float* __restrict__ s2_g,
                                               const float* __restrict__ scomp_g,
                                               const float* __restrict__ Pg,
                                               const float* __restrict__ KV,
                                               float* __restrict__ Out) {
    __shared__ float sqT[Dd * SRT];   // sigmoid(q) transposed; reused as masked S^T
    __shared__ float skb[Dd * SRT];   // KV-prefix [d][m]
    __shared__ float vsm[C * SRT];    // v (scomp folded later? no: raw v row-major, scomp in ST)
    __shared__ float lsc[C], s2l[C];
    int b = blockIdx.x, s = b / NC, c = b % NC;
    int n = s / Hh, h = s % Hh, t = threadIdx.x;
    int tx = t & 15, ty = t >> 4, i0 = 4 * ty, m0 = 4 * tx;

    if (t < 64) lsc[t] = scomp_g[s * Ll + c * C + t];
    else if (t < 128) s2l[t - 64] = s2_g[s * Ll + c * C + (t - 64)];

#pragma unroll
    for (int j = 0; j < 4; j++) {
        int flat = 4 * t + 1024 * j, i = flat >> 6, d0 = flat & 63;
        int id = gidx(n, c * C + i, h, d0);
        float4 q4 = *(const float4*)&Q[id];
        float4 v4 = *(const float4*)&V[id];
        float4 kv4 = *(const float4*)&KV[(size_t)b * 4096 + flat];
        sqT[(d0 + 0) * SRT + i] = sigf(q4.x);
        sqT[(d0 + 1) * SRT + i] = sigf(q4.y);
        sqT[(d0 + 2) * SRT + i] = sigf(q4.z);
        sqT[(d0 + 3) * SRT + i] = sigf(q4.w);
        *(float4*)&vsm[i * SRT + d0] = v4;
        *(float4*)&skb[i * SRT + d0] = kv4;   // here i=flat>>6 is the d-row of KV, d0 is m
    }
    // early P loads (latency hidden behind matmul1)
    float4 p4[4];
#pragma unroll
    for (int r = 0; r < 4; r++) p4[r] = *(const float4*)&Pg[(size_t)b * 4096 + (i0 + r) * 64 + m0];
    __syncthreads();

    float acc[4][4] = {};
    for (int d = 0; d < Dd; d++) {   // matmul1: sq^T x KVp
        float4 a = *(const float4*)&sqT[d * SRT + i0];
        float4 bb = *(const float4*)&skb[d * SRT + m0];
#pragma unroll
        for (int r = 0; r < 4; r++)
#pragma unroll
            for (int cc = 0; cc < 4; cc++) acc[r][cc] += fc(a, r) * fc(bb, cc);
    }
    __syncthreads();   // done reading sqT

    // masked S^T with scomp folded: ST[j][i] = (j<=i) ? P[i][j]*scomp_j : 0
#pragma unroll
    for (int cc = 0; cc < 4; cc++) {
        int j = m0 + cc;
        float lj = lsc[j];
        float4 v;
        v.x = (j <= i0 + 0) ? fc(p4[0], cc) * lj : 0.f;
        v.y = (j <= i0 + 1) ? fc(p4[1], cc) * lj : 0.f;
        v.z = (j <= i0 + 2) ? fc(p4[2], cc) * lj : 0.f;
        v.w = (j <= i0 + 3) ? fc(p4[3], cc) * lj : 0.f;
        *(float4*)&sqT[j * SRT + i0] = v;
    }
    __syncthreads();

    for (int j = 0; j < C; j++) {   // matmul2: ST^T x v
        float4 a = *(const float4*)&sqT[j * SRT + i0];
        float4 bb = *(const float4*)&vsm[j * SRT + m0];
#pragma unroll
        for (int r = 0; r < 4; r++)
#pragma unroll
            for (int cc = 0; cc < 4; cc++) acc[r][cc] += fc(a, r) * fc(bb, cc);
    }
#pragma unroll
    for (int r = 0; r < 4; r++) {
        float sf = s2l[i0 + r];
        float4 o = {acc[r][0] * sf, acc[r][1] * sf, acc[r][2] * sf, acc[r][3] * sf};
        *(float4*)&Out[gidx(n, c * C + i0 + r, h, m0)] = o;
    }
}

extern "C" void kernel_launch(void* const* d_in, const int* in_sizes, int n_in,
                              void* d_out, int out_size, void* d_ws, size_t ws_size,
                              hipStream_t stream) {
    const float* Q = (const float*)d_in[0];
    const float* K = (const float*)d_in[1];
    const float* V = (const float*)d_in[2];
    float* Out = (float*)d_out;

    float* ws    = (float*)d_ws;
    float* SK    = ws;                  // SC*64
    float* SQ    = SK    + SC * 64;
    float* SKso  = SQ    + SC * 64;
    float* SQsi  = SKso  + SC * 64;
    float* si_g  = SQsi  + SC * 64;     // S*Ll each
    float* so_g  = si_g  + S * Ll;
    float* s2_g  = so_g  + S * Ll;
    float* e_g   = s2_g  + S * Ll;
    float* ecum_g= e_g   + S * Ll;
    float* scomp = ecum_g+ S * Ll;
    float* Tcs   = scomp + S * Ll;      // SC
    float* Pg    = Tcs   + SC;          // SC*4096
    float* KV    = Pg    + (size_t)SC * 4096;

    k_sums<<<SC, 256, 0, stream>>>(Q, K, SK, SQ);
    k_pass1<<<SC, 256, 0, stream>>>(Q, K, SK, SQ, SKso, SQsi, si_g, so_g, Pg);
    k_pass2<<<SC, 256, 0, stream>>>(Q, K, SKso, SQsi, si_g, so_g, Pg, s2_g, e_g, ecum_g, Tcs);
    k_kv<<<SC, 256, 0, stream>>>(K, V, e_g, ecum_g, Tcs, scomp, KV);
    k_prefixKV<<<256, 256, 0, stream>>>(KV);
    k_final<<<SC, 256, 0, stream>>>(Q, V, s2_g, scomp, Pg, KV, Out);
}

// Round 5
// 123.173 us; speedup vs baseline: 3.0473x; 1.1354x over previous
//
#include <hip/hip_runtime.h>
#include <math.h>

// Problem constants (fixed by reference setup_inputs)
constexpr int Nn = 2, Hh = 8, Ll = 2048, Dd = 64;
constexpr int S  = Nn * Hh;      // 16 sequences
constexpr int C  = 64;           // chunk length
constexpr int NC = Ll / C;       // 32 chunks/seq
constexpr int SC = S * NC;       // 512 chunk-blocks

constexpr int SRT = 68;          // stride for transposed operand tiles (16B-aligned rows)
constexpr int SRP = 65;          // stride for score matrix P (scalar scans conflict-free)

#define EPSF 1e-6f

__device__ __forceinline__ float sigf(float x) { return 1.0f / (1.0f + expf(-x)); }

__device__ __forceinline__ float waveRed(float v) {
#pragma unroll
    for (int off = 32; off > 0; off >>= 1) v += __shfl_xor(v, off, 64);
    return v;
}

__device__ __forceinline__ int gidx(int n, int l, int h, int d) {
    return ((n * Ll + l) * Hh + h) * Dd + d;
}

__device__ __forceinline__ float fc(const float4& v, int u) { return ((const float*)&v)[u]; }

// K1: per-chunk sums of sigmoid(k), sigmoid(q).
__global__ __launch_bounds__(256) void k_sums(const float* __restrict__ Q,
                                              const float* __restrict__ K,
                                              float* __restrict__ SK, float* __restrict__ SQ) {
    __shared__ float scr[2048];
    int b = blockIdx.x, s = b / NC, c = b % NC;
    int n = s / Hh, h = s % Hh, t = threadIdx.x;
    int d0 = (4 * t) & 63, ig = t >> 4;
    float psk[4] = {0, 0, 0, 0}, psq[4] = {0, 0, 0, 0};
#pragma unroll
    for (int j = 0; j < 4; j++) {
        int i = ig + 16 * j;
        int id = gidx(n, c * C + i, h, d0);
        float4 q4 = *(const float4*)&Q[id];
        float4 k4 = *(const float4*)&K[id];
        psq[0] += sigf(q4.x); psq[1] += sigf(q4.y); psq[2] += sigf(q4.z); psq[3] += sigf(q4.w);
        psk[0] += sigf(k4.x); psk[1] += sigf(k4.y); psk[2] += sigf(k4.z); psk[3] += sigf(k4.w);
    }
#pragma unroll
    for (int r = 0; r < 4; r++) {
        scr[ig * 64 + d0 + r] = psk[r];
        scr[1024 + ig * 64 + d0 + r] = psq[r];
    }
    __syncthreads();
    if (t < 64) {
        float v = 0.f;
        for (int g = 0; g < 16; g++) v += scr[g * 64 + t];
        SK[b * 64 + t] = v;
    } else if (t < 128) {
        int d = t - 64; float v = 0.f;
        for (int g = 0; g < 16; g++) v += scr[1024 + g * 64 + d];
        SQ[b * 64 + d] = v;
    }
}

// K2: pass1 — stage, P matmul (->Pg), si/so, rw1/rw2 triangular sums, SKso/SQsi sums.
__global__ __launch_bounds__(256) void k_pass1(const float* __restrict__ Q,
                                               const float* __restrict__ K,
                                               const float* __restrict__ SK,
                                               const float* __restrict__ SQ,
                                               float* __restrict__ SKso,
                                               float* __restrict__ SQsi,
                                               float* __restrict__ si_g,
                                               float* __restrict__ rw1_g,
                                               float* __restrict__ rw2_g,
                                               float* __restrict__ Pg) {
    __shared__ float sqT[Dd * SRT];
    __shared__ float skT[Dd * SRT];
    __shared__ float P[C * SRP];      // low 512 floats double as prefix scratch pre-matmul
    __shared__ float colK[C], colQ[C], pk[Dd], pq[Dd], lsi[C], lso[C];
    int b = blockIdx.x, s = b / NC, c = b % NC;
    int n = s / Hh, h = s % Hh, t = threadIdx.x;
    int tx = t & 15, ty = t >> 4, i0 = 4 * ty, j0 = 4 * tx;

    // stage
#pragma unroll
    for (int j = 0; j < 4; j++) {
        int flat = 4 * t + 1024 * j, i = flat >> 6, d0 = flat & 63;
        int id = gidx(n, c * C + i, h, d0);
        float4 q4 = *(const float4*)&Q[id];
        float4 k4 = *(const float4*)&K[id];
        sqT[(d0 + 0) * SRT + i] = sigf(q4.x);
        sqT[(d0 + 1) * SRT + i] = sigf(q4.y);
        sqT[(d0 + 2) * SRT + i] = sigf(q4.z);
        sqT[(d0 + 3) * SRT + i] = sigf(q4.w);
        skT[(d0 + 0) * SRT + i] = sigf(k4.x);
        skT[(d0 + 1) * SRT + i] = sigf(k4.y);
        skT[(d0 + 2) * SRT + i] = sigf(k4.z);
        skT[(d0 + 3) * SRT + i] = sigf(k4.w);
    }
    // parallel prefix partials: all 256 threads, <=8 independent loads each
    {
        int d = t & 63, g = t >> 6;
        float pa = 0.f, pb = 0.f;
        for (int cp = g; cp < c; cp += 4) {
            pa += SK[(s * NC + cp) * 64 + d];
            pb += SQ[(s * NC + cp) * 64 + d];
        }
        P[g * 64 + d] = pa;
        P[256 + g * 64 + d] = pb;
    }
    __syncthreads();
    if (t < 64) {
        pk[t] = P[t] + P[64 + t] + P[128 + t] + P[192 + t];
    } else if (t < 128) {
        int d = t - 64;
        pq[d] = P[256 + d] + P[320 + d] + P[384 + d] + P[448 + d];
    } else if (t < 192) {
        int i = t - 128; float v = 0.f;
        for (int d = 0; d < Dd; d++) v += skT[d * SRT + i];
        colK[i] = v;
    } else {
        int i = t - 192; float v = 0.f;
        for (int d = 0; d < Dd; d++) v += sqT[d * SRT + i];
        colQ[i] = v;
    }
    __syncthreads();

    // P matmul
    float acc[4][4] = {};
    for (int d = 0; d < Dd; d++) {
        float4 a = *(const float4*)&sqT[d * SRT + i0];
        float4 bb = *(const float4*)&skT[d * SRT + j0];
#pragma unroll
        for (int r = 0; r < 4; r++)
#pragma unroll
            for (int cc = 0; cc < 4; cc++) acc[r][cc] += fc(a, r) * fc(bb, cc);
    }
#pragma unroll
    for (int r = 0; r < 4; r++) {
#pragma unroll
        for (int cc = 0; cc < 4; cc++) P[(i0 + r) * SRP + (j0 + cc)] = acc[r][cc];
        float4 o = {acc[r][0], acc[r][1], acc[r][2], acc[r][3]};
        *(float4*)&Pg[(size_t)b * 4096 + (i0 + r) * 64 + j0] = o;
    }
    __syncthreads();

    // si/so
    if (t < 64) {
        int i = t, l = c * C + i;
        float r1 = 0.f, r2 = 0.f;
        for (int j = 0; j <= i; j++) {
            r1 += P[i * SRP + j] + EPSF * colK[j];
            r2 += P[j * SRP + i] + EPSF * colQ[j];
        }
        float b1 = 0.f, b2 = 0.f;
        for (int d = 0; d < Dd; d++) {
            b1 += (sqT[d * SRT + i] + EPSF) * (pk[d] + EPSF);
            b2 += (skT[d * SRT + i] + EPSF) * (pq[d] + EPSF);
        }
        float nf = (float)(l + 1);
        float siF = nf / (b1 + r1), soF = nf / (b2 + r2);
        si_g[s * Ll + l] = siF;
        lsi[i] = siF; lso[i] = soF;
    }
    __syncthreads();

    // rw1/rw2 triangular sums + SKso/SQsi chunk sums (4 groups in parallel)
    if (t < 64) {
        int i = t;
        float v = 0.f;
        for (int j = 0; j <= i; j++) v += lso[j] * (P[i * SRP + j] + EPSF * colK[j]);
        rw1_g[s * Ll + c * C + i] = v;
    } else if (t < 128) {
        int i = t - 64;
        float v = 0.f;
        for (int j = 0; j <= i; j++) v += lsi[j] * (P[j * SRP + i] + EPSF * colQ[j]);
        rw2_g[s * Ll + c * C + i] = v;
    } else if (t < 192) {
        int d = t - 128; float v = 0.f;
        for (int i = 0; i < C; i++) v += skT[d * SRT + i] * lso[i];
        SKso[b * 64 + d] = v;
    } else {
        int d = t - 192; float v = 0.f;
        for (int i = 0; i < C; i++) v += sqT[d * SRT + i] * lsi[i];
        SQsi[b * 64 + d] = v;
    }
}

// K3: light pass2 — no staging, no P. b1/b2 matvec direct from global.
__global__ __launch_bounds__(256) void k_pass2(const float* __restrict__ Q,
                                               const float* __restrict__ K,
                                               const float* __restrict__ SKso,
                                               const float* __restrict__ SQsi,
                                               const float* __restrict__ si_g,
                                               const float* __restrict__ rw1_g,
                                               const float* __restrict__ rw2_g,
                                               float* __restrict__ s2_g,
                                               float* __restrict__ e_g,
                                               float* __restrict__ ecum_g,
                                               float* __restrict__ Tcs) {
    __shared__ float scr[512];
    __shared__ float pks[Dd], pqs[Dd], le[C];
    int b = blockIdx.x, s = b / NC, c = b % NC;
    int n = s / Hh, h = s % Hh, t = threadIdx.x;

    {   // parallel prefix of SKso/SQsi
        int d = t & 63, g = t >> 6;
        float pa = 0.f, pb = 0.f;
        for (int cp = g; cp < c; cp += 4) {
            pa += SKso[(s * NC + cp) * 64 + d];
            pb += SQsi[(s * NC + cp) * 64 + d];
        }
        scr[g * 64 + d] = pa;
        scr[256 + g * 64 + d] = pb;
    }
    __syncthreads();
    if (t < 64) pks[t] = scr[t] + scr[64 + t] + scr[128 + t] + scr[192 + t];
    else if (t < 128) {
        int d = t - 64;
        pqs[d] = scr[256 + d] + scr[320 + d] + scr[384 + d] + scr[448 + d];
    }
    __syncthreads();

    // b1/b2 matvec: 4 lanes per row i
    int i = t >> 2, g = t & 3, l = c * C + i;
    float b1 = 0.f, b2 = 0.f;
#pragma unroll
    for (int u = 0; u < 4; u++) {
        int d = g * 16 + 4 * u;
        float4 q4 = *(const float4*)&Q[gidx(n, l, h, d)];
        float4 k4 = *(const float4*)&K[gidx(n, l, h, d)];
#pragma unroll
        for (int w = 0; w < 4; w++) {
            b1 += (sigf(fc(q4, w)) + EPSF) * (pks[d + w] + EPSF);
            b2 += (sigf(fc(k4, w)) + EPSF) * (pqs[d + w] + EPSF);
        }
    }
    b1 += __shfl_xor(b1, 1, 64); b1 += __shfl_xor(b1, 2, 64);
    b2 += __shfl_xor(b2, 1, 64); b2 += __shfl_xor(b2, 2, 64);
    if (g == 0) {
        float nf = (float)(l + 1);
        float cs  = (b1 + rw1_g[s * Ll + l]) / nf;
        float csr = (b2 + rw2_g[s * Ll + l]) / nf;
        csr = fminf(fmaxf(csr, -1.f), 1.f);
        float e = expf(csr);
        float sal = 1.0f / (1.0f + expf(-cs));
        s2_g[s * Ll + l] = si_g[s * Ll + l] / nf * sal;
        e_g[s * Ll + l] = e;
        le[i] = e;
    }
    __syncthreads();
    if (t < 64) {
        float run = le[t];
#pragma unroll
        for (int off = 1; off < 64; off <<= 1) {
            float o = __shfl_up(run, off, 64);
            if (t >= off) run += o;
        }
        ecum_g[s * Ll + c * C + t] = run;
        if (t == 63) Tcs[b] = run;
    }
}

// K4: scomp (inline Tcs prefix) + chunk KV matmul.
__global__ __launch_bounds__(256) void k_kv(const float* __restrict__ K,
                                            const float* __restrict__ V,
                                            const float* __restrict__ e_g,
                                            const float* __restrict__ ecum_g,
                                            const float* __restrict__ Tcs,
                                            float* __restrict__ scomp_g,
                                            float* __restrict__ KV) {
    __shared__ float lk[C][Dd];
    __shared__ float lvs[C][Dd];
    __shared__ float lsc[C];
    __shared__ float pcsv;
    int b = blockIdx.x, s = b / NC, c = b % NC;
    int n = s / Hh, h = s % Hh, t = threadIdx.x;
    if (t < 64) {
        float v = (t < c) ? Tcs[s * NC + t] : 0.f;
        v = waveRed(v);
        if (t == 0) pcsv = v;
    }
    __syncthreads();
    if (t < 64) {
        int l = c * C + t;
        float ls = e_g[s * Ll + l] / (pcsv + ecum_g[s * Ll + l]) * (float)(l + 1);
        lsc[t] = ls;
        scomp_g[s * Ll + l] = ls;
    }
    __syncthreads();
#pragma unroll
    for (int j = 0; j < 16; j++) {
        int flat = t + 256 * j, i = flat >> 6, d = flat & 63;
        int id = gidx(n, c * C + i, h, d);
        lk[i][d]  = sigf(K[id]);
        lvs[i][d] = V[id] * lsc[i];
    }
    __syncthreads();
    int tx = t & 15, ty = t >> 4, m0 = tx * 4, d0 = ty * 4;
    float acc[4][4] = {};
    for (int i = 0; i < C; i++) {
        float4 k4 = *(const float4*)&lk[i][d0];
        float4 v4 = *(const float4*)&lvs[i][m0];
#pragma unroll
        for (int r = 0; r < 4; r++)
#pragma unroll
            for (int cc = 0; cc < 4; cc++) acc[r][cc] += fc(k4, r) * fc(v4, cc);
    }
    float* dst = &KV[(size_t)b * 4096];
#pragma unroll
    for (int r = 0; r < 4; r++) {
        float4 o = {acc[r][0], acc[r][1], acc[r][2], acc[r][3]};
        *(float4*)&dst[(d0 + r) * 64 + m0] = o;
    }
}

// K5: exclusive chunk-prefix of KV (register-preload). grid=256.
__global__ __launch_bounds__(256) void k_prefixKV(float* __restrict__ KV) {
    int bx = blockIdx.x, s = bx >> 4, sub = bx & 15;
    int e0 = sub * 256 + threadIdx.x;
    float x[NC];
#pragma unroll
    for (int cp = 0; cp < NC; cp++)
        x[cp] = KV[(size_t)(s * NC + cp) * 4096 + e0];
    float r = 0.f;
#pragma unroll
    for (int cp = 0; cp < NC; cp++) {
        float tv = x[cp];
        KV[(size_t)(s * NC + cp) * 4096 + e0] = r;
        r += tv;
    }
}

// K6: final — out = s2 * (sq·KVp + maskedP·scomp·v).
__global__ __launch_bounds__(256) void k_final(const float* __restrict__ Q,
                                               const float* __restrict__ V,
                                               const float* __restrict__ s2_g,
                                               const float* __restrict__ scomp_g,
                                               const float* __restrict__ Pg,
                                               const float* __restrict__ KV,
                                               float* __restrict__ Out) {
    __shared__ float sqT[Dd * SRT];   // sigmoid(q) transposed; reused as masked S^T
    __shared__ float skb[Dd * SRT];   // KV-prefix [d][m]
    __shared__ float vsm[C * SRT];    // raw v row-major
    __shared__ float lsc[C], s2l[C];
    int b = blockIdx.x, s = b / NC, c = b % NC;
    int n = s / Hh, h = s % Hh, t = threadIdx.x;
    int tx = t & 15, ty = t >> 4, i0 = 4 * ty, m0 = 4 * tx;

    if (t < 64) lsc[t] = scomp_g[s * Ll + c * C + t];
    else if (t < 128) s2l[t - 64] = s2_g[s * Ll + c * C + (t - 64)];

#pragma unroll
    for (int j = 0; j < 4; j++) {
        int flat = 4 * t + 1024 * j, i = flat >> 6, d0 = flat & 63;
        int id = gidx(n, c * C + i, h, d0);
        float4 q4 = *(const float4*)&Q[id];
        float4 v4 = *(const float4*)&V[id];
        float4 kv4 = *(const float4*)&KV[(size_t)b * 4096 + flat];
        sqT[(d0 + 0) * SRT + i] = sigf(q4.x);
        sqT[(d0 + 1) * SRT + i] = sigf(q4.y);
        sqT[(d0 + 2) * SRT + i] = sigf(q4.z);
        sqT[(d0 + 3) * SRT + i] = sigf(q4.w);
        *(float4*)&vsm[i * SRT + d0] = v4;
        *(float4*)&skb[i * SRT + d0] = kv4;   // i = d-row of KV, d0 = m
    }
    float4 p4[4];
#pragma unroll
    for (int r = 0; r < 4; r++) p4[r] = *(const float4*)&Pg[(size_t)b * 4096 + (i0 + r) * 64 + m0];
    __syncthreads();

    float acc[4][4] = {};
    for (int d = 0; d < Dd; d++) {   // matmul1: sq^T x KVp
        float4 a = *(const float4*)&sqT[d * SRT + i0];
        float4 bb = *(const float4*)&skb[d * SRT + m0];
#pragma unroll
        for (int r = 0; r < 4; r++)
#pragma unroll
            for (int cc = 0; cc < 4; cc++) acc[r][cc] += fc(a, r) * fc(bb, cc);
    }
    __syncthreads();   // done reading sqT

#pragma unroll
    for (int cc = 0; cc < 4; cc++) {   // masked S^T with scomp folded
        int j = m0 + cc;
        float lj = lsc[j];
        float4 v;
        v.x = (j <= i0 + 0) ? fc(p4[0], cc) * lj : 0.f;
        v.y = (j <= i0 + 1) ? fc(p4[1], cc) * lj : 0.f;
        v.z = (j <= i0 + 2) ? fc(p4[2], cc) * lj : 0.f;
        v.w = (j <= i0 + 3) ? fc(p4[3], cc) * lj : 0.f;
        *(float4*)&sqT[j * SRT + i0] = v;
    }
    __syncthreads();

    for (int j = 0; j < C; j++) {   // matmul2: ST^T x v
        float4 a = *(const float4*)&sqT[j * SRT + i0];
        float4 bb = *(const float4*)&vsm[j * SRT + m0];
#pragma unroll
        for (int r = 0; r < 4; r++)
#pragma unroll
            for (int cc = 0; cc < 4; cc++) acc[r][cc] += fc(a, r) * fc(bb, cc);
    }
#pragma unroll
    for (int r = 0; r < 4; r++) {
        float sf = s2l[i0 + r];
        float4 o = {acc[r][0] * sf, acc[r][1] * sf, acc[r][2] * sf, acc[r][3] * sf};
        *(float4*)&Out[gidx(n, c * C + i0 + r, h, m0)] = o;
    }
}

extern "C" void kernel_launch(void* const* d_in, const int* in_sizes, int n_in,
                              void* d_out, int out_size, void* d_ws, size_t ws_size,
                              hipStream_t stream) {
    const float* Q = (const float*)d_in[0];
    const float* K = (const float*)d_in[1];
    const float* V = (const float*)d_in[2];
    float* Out = (float*)d_out;

    float* ws    = (float*)d_ws;
    float* SK    = ws;                  // SC*64
    float* SQ    = SK    + SC * 64;
    float* SKso  = SQ    + SC * 64;
    float* SQsi  = SKso  + SC * 64;
    float* si_g  = SQsi  + SC * 64;     // S*Ll each
    float* rw1_g = si_g  + S * Ll;
    float* rw2_g = rw1_g + S * Ll;
    float* s2_g  = rw2_g + S * Ll;
    float* e_g   = s2_g  + S * Ll;
    float* ecum_g= e_g   + S * Ll;
    float* scomp = ecum_g+ S * Ll;
    float* Tcs   = scomp + S * Ll;      // SC
    float* Pg    = Tcs   + SC;          // SC*4096
    float* KV    = Pg    + (size_t)SC * 4096;

    k_sums<<<SC, 256, 0, stream>>>(Q, K, SK, SQ);
    k_pass1<<<SC, 256, 0, stream>>>(Q, K, SK, SQ, SKso, SQsi, si_g, rw1_g, rw2_g, Pg);
    k_pass2<<<SC, 256, 0, stream>>>(Q, K, SKso, SQsi, si_g, rw1_g, rw2_g, s2_g, e_g, ecum_g, Tcs);
    k_kv<<<SC, 256, 0, stream>>>(K, V, e_g, ecum_g, Tcs, scomp, KV);
    k_prefixKV<<<256, 256, 0, stream>>>(KV);
    k_final<<<SC, 256, 0, stream>>>(Q, V, s2_g, scomp, Pg, KV, Out);
}

// Round 6
// 114.301 us; speedup vs baseline: 3.2838x; 1.0776x over previous
//
#include <hip/hip_runtime.h>
#include <math.h>

// Problem constants (fixed by reference setup_inputs)
constexpr int Nn = 2, Hh = 8, Ll = 2048, Dd = 64;
constexpr int S  = Nn * Hh;      // 16 sequences
constexpr int C  = 64;           // chunk length
constexpr int NC = Ll / C;       // 32 chunks/seq
constexpr int SC = S * NC;       // 512 chunk-blocks

constexpr int SB  = 72;          // bf16 LDS row stride (144 B = 16B-aligned rows, ~2-way banks)
constexpr int SRP = 65;          // fp32 score-matrix stride (scalar scans conflict-free)

#define EPSF 1e-6f

typedef __attribute__((ext_vector_type(8))) short short8;
typedef __attribute__((ext_vector_type(4))) float f32x4;
#define MFMA16(a, b, c) __builtin_amdgcn_mfma_f32_16x16x32_bf16(a, b, c, 0, 0, 0)

__device__ __forceinline__ float sigf(float x) { return 1.0f / (1.0f + expf(-x)); }

__device__ __forceinline__ float waveRed(float v) {
#pragma unroll
    for (int off = 32; off > 0; off >>= 1) v += __shfl_xor(v, off, 64);
    return v;
}

__device__ __forceinline__ int gidx(int n, int l, int h, int d) {
    return ((n * Ll + l) * Hh + h) * Dd + d;
}

__device__ __forceinline__ float fc(const float4& v, int u) { return ((const float*)&v)[u]; }

__device__ __forceinline__ unsigned short f2bf(float x) {
    unsigned int u = __float_as_uint(x);
    unsigned int r = (u + 0x7fffu + ((u >> 16) & 1u)) >> 16;   // RNE
    return (unsigned short)r;
}
__device__ __forceinline__ unsigned int pack2(float lo, float hi) {
    return (unsigned int)f2bf(lo) | ((unsigned int)f2bf(hi) << 16);
}
__device__ __forceinline__ float bf2f(unsigned short u) {
    return __uint_as_float(((unsigned int)u) << 16);
}

// K1: per-chunk sums of sigmoid(k), sigmoid(q).
__global__ __launch_bounds__(256) void k_sums(const float* __restrict__ Q,
                                              const float* __restrict__ K,
                                              float* __restrict__ SK, float* __restrict__ SQ) {
    __shared__ float scr[2048];
    int b = blockIdx.x, s = b / NC, c = b % NC;
    int n = s / Hh, h = s % Hh, t = threadIdx.x;
    int d0 = (4 * t) & 63, ig = t >> 4;
    float psk[4] = {0, 0, 0, 0}, psq[4] = {0, 0, 0, 0};
#pragma unroll
    for (int j = 0; j < 4; j++) {
        int i = ig + 16 * j;
        int id = gidx(n, c * C + i, h, d0);
        float4 q4 = *(const float4*)&Q[id];
        float4 k4 = *(const float4*)&K[id];
        psq[0] += sigf(q4.x); psq[1] += sigf(q4.y); psq[2] += sigf(q4.z); psq[3] += sigf(q4.w);
        psk[0] += sigf(k4.x); psk[1] += sigf(k4.y); psk[2] += sigf(k4.z); psk[3] += sigf(k4.w);
    }
#pragma unroll
    for (int r = 0; r < 4; r++) {
        scr[ig * 64 + d0 + r] = psk[r];
        scr[1024 + ig * 64 + d0 + r] = psq[r];
    }
    __syncthreads();
    if (t < 64) {
        float v = 0.f;
        for (int g = 0; g < 16; g++) v += scr[g * 64 + t];
        SK[b * 64 + t] = v;
    } else if (t < 128) {
        int d = t - 64; float v = 0.f;
        for (int g = 0; g < 16; g++) v += scr[1024 + g * 64 + d];
        SQ[b * 64 + d] = v;
    }
}

// K2: pass1 — stage bf16, MFMA P (->LDS fp32 + Pg), si/so, rw1/rw2, SKso/SQsi.
__global__ __launch_bounds__(256) void k_pass1(const float* __restrict__ Q,
                                               const float* __restrict__ K,
                                               const float* __restrict__ SK,
                                               const float* __restrict__ SQ,
                                               float* __restrict__ SKso,
                                               float* __restrict__ SQsi,
                                               float* __restrict__ si_g,
                                               float* __restrict__ rw1_g,
                                               float* __restrict__ rw2_g,
                                               float* __restrict__ Pg) {
    __shared__ __align__(16) unsigned short sqB[C * SB];   // [i][d] bf16
    __shared__ __align__(16) unsigned short skB[C * SB];
    __shared__ float P[C * SRP];      // fp32; low 2560 doubles as scratch pre-matmul
    __shared__ float colK[C], colQ[C], pk[Dd], pq[Dd], lsi[C], lso[C];
    int b = blockIdx.x, s = b / NC, c = b % NC;
    int n = s / Hh, h = s % Hh, t = threadIdx.x;

    // stage (natural row-major bf16) + per-thread row-sum partials
#pragma unroll
    for (int j = 0; j < 4; j++) {
        int flat = 4 * t + 1024 * j, i = flat >> 6, d0 = flat & 63;
        int id = gidx(n, c * C + i, h, d0);
        float4 q4 = *(const float4*)&Q[id];
        float4 k4 = *(const float4*)&K[id];
        float sq0 = sigf(q4.x), sq1 = sigf(q4.y), sq2 = sigf(q4.z), sq3 = sigf(q4.w);
        float sk0 = sigf(k4.x), sk1 = sigf(k4.y), sk2 = sigf(k4.z), sk3 = sigf(k4.w);
        *(uint2*)&sqB[i * SB + d0] = make_uint2(pack2(sq0, sq1), pack2(sq2, sq3));
        *(uint2*)&skB[i * SB + d0] = make_uint2(pack2(sk0, sk1), pack2(sk2, sk3));
        P[i * 16 + (t & 15)]        = sk0 + sk1 + sk2 + sk3;   // scrColK
        P[1024 + i * 16 + (t & 15)] = sq0 + sq1 + sq2 + sq3;   // scrColQ
    }
    {   // cross-chunk prefix partials (4 groups)
        int d = t & 63, g = t >> 6;
        float pa = 0.f, pb = 0.f;
        for (int cp = g; cp < c; cp += 4) {
            pa += SK[(s * NC + cp) * 64 + d];
            pb += SQ[(s * NC + cp) * 64 + d];
        }
        P[2048 + g * 64 + d] = pa;
        P[2304 + g * 64 + d] = pb;
    }
    __syncthreads();
    if (t < 64) {
        float v = 0.f;
#pragma unroll
        for (int u = 0; u < 16; u++) v += P[t * 16 + u];
        colK[t] = v;
    } else if (t < 128) {
        int i = t - 64; float v = 0.f;
#pragma unroll
        for (int u = 0; u < 16; u++) v += P[1024 + i * 16 + u];
        colQ[i] = v;
    } else if (t < 192) {
        int d = t - 128;
        pk[d] = P[2048 + d] + P[2048 + 64 + d] + P[2048 + 128 + d] + P[2048 + 192 + d];
    } else {
        int d = t - 192;
        pq[d] = P[2304 + d] + P[2304 + 64 + d] + P[2304 + 128 + d] + P[2304 + 192 + d];
    }
    __syncthreads();

    // MFMA: P = sq · sk^T  (wave w = row-block)
    {
        int w = t >> 6, lane = t & 63, m = lane & 15, q = lane >> 4;
        f32x4 acc[4] = {{0,0,0,0},{0,0,0,0},{0,0,0,0},{0,0,0,0}};
#pragma unroll
        for (int kk = 0; kk < 64; kk += 32) {
            short8 a = *(const short8*)&sqB[(16 * w + m) * SB + kk + q * 8];
#pragma unroll
            for (int J = 0; J < 4; J++) {
                short8 bb = *(const short8*)&skB[(16 * J + m) * SB + kk + q * 8];
                acc[J] = MFMA16(a, bb, acc[J]);
            }
        }
#pragma unroll
        for (int J = 0; J < 4; J++)
#pragma unroll
            for (int r = 0; r < 4; r++) {
                int io = 16 * w + 4 * q + r, jo = 16 * J + m;
                P[io * SRP + jo] = acc[J][r];
                Pg[(size_t)b * 4096 + io * 64 + jo] = acc[J][r];
            }
    }
    __syncthreads();

    // si/so  (b1/b2 dots read bf16 rows)
    if (t < 64) {
        int i = t, l = c * C + i;
        float r1 = 0.f, r2 = 0.f;
        for (int j = 0; j <= i; j++) {
            r1 += P[i * SRP + j] + EPSF * colK[j];
            r2 += P[j * SRP + i] + EPSF * colQ[j];
        }
        float b1 = 0.f, b2 = 0.f;
        for (int d = 0; d < Dd; d++) {
            b1 += (bf2f(sqB[i * SB + d]) + EPSF) * (pk[d] + EPSF);
            b2 += (bf2f(skB[i * SB + d]) + EPSF) * (pq[d] + EPSF);
        }
        float nf = (float)(l + 1);
        float siF = nf / (b1 + r1), soF = nf / (b2 + r2);
        si_g[s * Ll + l] = siF;
        lsi[i] = siF; lso[i] = soF;
    }
    __syncthreads();

    // rw1/rw2 + SKso/SQsi (4 groups)
    if (t < 64) {
        int i = t; float v = 0.f;
        for (int j = 0; j <= i; j++) v += lso[j] * (P[i * SRP + j] + EPSF * colK[j]);
        rw1_g[s * Ll + c * C + i] = v;
    } else if (t < 128) {
        int i = t - 64; float v = 0.f;
        for (int j = 0; j <= i; j++) v += lsi[j] * (P[j * SRP + i] + EPSF * colQ[j]);
        rw2_g[s * Ll + c * C + i] = v;
    } else if (t < 192) {
        int d = t - 128; float v = 0.f;
        for (int i = 0; i < C; i++) v += bf2f(skB[i * SB + d]) * lso[i];
        SKso[b * 64 + d] = v;
    } else {
        int d = t - 192; float v = 0.f;
        for (int i = 0; i < C; i++) v += bf2f(sqB[i * SB + d]) * lsi[i];
        SQsi[b * 64 + d] = v;
    }
}

// K3: light pass2 — prefix + direct matvec (fp32, unchanged from R5).
__global__ __launch_bounds__(256) void k_pass2(const float* __restrict__ Q,
                                               const float* __restrict__ K,
                                               const float* __restrict__ SKso,
                                               const float* __restrict__ SQsi,
                                               const float* __restrict__ si_g,
                                               const float* __restrict__ rw1_g,
                                               const float* __restrict__ rw2_g,
                                               float* __restrict__ s2_g,
                                               float* __restrict__ e_g,
                                               float* __restrict__ ecum_g,
                                               float* __restrict__ Tcs) {
    __shared__ float scr[512];
    __shared__ float pks[Dd], pqs[Dd], le[C];
    int b = blockIdx.x, s = b / NC, c = b % NC;
    int n = s / Hh, h = s % Hh, t = threadIdx.x;

    {
        int d = t & 63, g = t >> 6;
        float pa = 0.f, pb = 0.f;
        for (int cp = g; cp < c; cp += 4) {
            pa += SKso[(s * NC + cp) * 64 + d];
            pb += SQsi[(s * NC + cp) * 64 + d];
        }
        scr[g * 64 + d] = pa;
        scr[256 + g * 64 + d] = pb;
    }
    __syncthreads();
    if (t < 64) pks[t] = scr[t] + scr[64 + t] + scr[128 + t] + scr[192 + t];
    else if (t < 128) {
        int d = t - 64;
        pqs[d] = scr[256 + d] + scr[320 + d] + scr[384 + d] + scr[448 + d];
    }
    __syncthreads();

    int i = t >> 2, g = t & 3, l = c * C + i;
    float b1 = 0.f, b2 = 0.f;
#pragma unroll
    for (int u = 0; u < 4; u++) {
        int d = g * 16 + 4 * u;
        float4 q4 = *(const float4*)&Q[gidx(n, l, h, d)];
        float4 k4 = *(const float4*)&K[gidx(n, l, h, d)];
#pragma unroll
        for (int w = 0; w < 4; w++) {
            b1 += (sigf(fc(q4, w)) + EPSF) * (pks[d + w] + EPSF);
            b2 += (sigf(fc(k4, w)) + EPSF) * (pqs[d + w] + EPSF);
        }
    }
    b1 += __shfl_xor(b1, 1, 64); b1 += __shfl_xor(b1, 2, 64);
    b2 += __shfl_xor(b2, 1, 64); b2 += __shfl_xor(b2, 2, 64);
    if (g == 0) {
        float nf = (float)(l + 1);
        float cs  = (b1 + rw1_g[s * Ll + l]) / nf;
        float csr = (b2 + rw2_g[s * Ll + l]) / nf;
        csr = fminf(fmaxf(csr, -1.f), 1.f);
        float e = expf(csr);
        float sal = 1.0f / (1.0f + expf(-cs));
        s2_g[s * Ll + l] = si_g[s * Ll + l] / nf * sal;
        e_g[s * Ll + l] = e;
        le[i] = e;
    }
    __syncthreads();
    if (t < 64) {
        float run = le[t];
#pragma unroll
        for (int off = 1; off < 64; off <<= 1) {
            float o = __shfl_up(run, off, 64);
            if (t >= off) run += o;
        }
        ecum_g[s * Ll + c * C + t] = run;
        if (t == 63) Tcs[b] = run;
    }
}

// K4: scomp + MFMA chunk KV^T[m][d] (transposed-staged skT[d][i], vsT[m][i]).
__global__ __launch_bounds__(256) void k_kv(const float* __restrict__ K,
                                            const float* __restrict__ V,
                                            const float* __restrict__ e_g,
                                            const float* __restrict__ ecum_g,
                                            const float* __restrict__ Tcs,
                                            float* __restrict__ scomp_g,
                                            float* __restrict__ KVT) {
    __shared__ __align__(16) unsigned short skT[Dd * SB];   // [d][i]
    __shared__ __align__(16) unsigned short vsT[Dd * SB];   // [m][i]
    __shared__ float lsc[C];
    __shared__ float pcsv;
    int b = blockIdx.x, s = b / NC, c = b % NC;
    int n = s / Hh, h = s % Hh, t = threadIdx.x;
    if (t < 64) {
        float v = (t < c) ? Tcs[s * NC + t] : 0.f;
        v = waveRed(v);
        if (t == 0) pcsv = v;
    }
    __syncthreads();
    if (t < 64) {
        int l = c * C + t;
        float ls = e_g[s * Ll + l] / (pcsv + ecum_g[s * Ll + l]) * (float)(l + 1);
        lsc[t] = ls;
        scomp_g[s * Ll + l] = ls;
    }
    __syncthreads();

    // transposed staging: thread owns rows i0..i0+3 at one d0 quad
    {
        int i0 = (t & 15) * 4, d0 = (((t >> 4) & 3) + 4 * (t >> 6)) * 4;
        float4 kr[4], vr[4];
#pragma unroll
        for (int r = 0; r < 4; r++) {
            int id = gidx(n, c * C + i0 + r, h, d0);
            kr[r] = *(const float4*)&K[id];
            vr[r] = *(const float4*)&V[id];
        }
        float sc0 = lsc[i0], sc1 = lsc[i0 + 1], sc2 = lsc[i0 + 2], sc3 = lsc[i0 + 3];
#pragma unroll
        for (int u = 0; u < 4; u++) {
            *(uint2*)&skT[(d0 + u) * SB + i0] = make_uint2(
                pack2(sigf(fc(kr[0], u)), sigf(fc(kr[1], u))),
                pack2(sigf(fc(kr[2], u)), sigf(fc(kr[3], u))));
            *(uint2*)&vsT[(d0 + u) * SB + i0] = make_uint2(
                pack2(fc(vr[0], u) * sc0, fc(vr[1], u) * sc1),
                pack2(fc(vr[2], u) * sc2, fc(vr[3], u) * sc3));
        }
    }
    __syncthreads();

    // MFMA: KVT[m][d] = sum_i vsT[m][i] * skT[d][i]
    {
        int w = t >> 6, lane = t & 63, m = lane & 15, q = lane >> 4;
        f32x4 acc[4] = {{0,0,0,0},{0,0,0,0},{0,0,0,0},{0,0,0,0}};
#pragma unroll
        for (int kk = 0; kk < 64; kk += 32) {
            short8 a = *(const short8*)&vsT[(16 * w + m) * SB + kk + q * 8];
#pragma unroll
            for (int J = 0; J < 4; J++) {
                short8 bb = *(const short8*)&skT[(16 * J + m) * SB + kk + q * 8];
                acc[J] = MFMA16(a, bb, acc[J]);
            }
        }
#pragma unroll
        for (int J = 0; J < 4; J++)
#pragma unroll
            for (int r = 0; r < 4; r++)
                KVT[(size_t)b * 4096 + (16 * w + 4 * q + r) * 64 + 16 * J + m] = acc[J][r];
    }
}

// K5: exclusive chunk-prefix of KVT (elementwise, register-preload). grid=256.
__global__ __launch_bounds__(256) void k_prefixKV(float* __restrict__ KVT) {
    int bx = blockIdx.x, s = bx >> 4, sub = bx & 15;
    int e0 = sub * 256 + threadIdx.x;
    float x[NC];
#pragma unroll
    for (int cp = 0; cp < NC; cp++)
        x[cp] = KVT[(size_t)(s * NC + cp) * 4096 + e0];
    float r = 0.f;
#pragma unroll
    for (int cp = 0; cp < NC; cp++) {
        float tv = x[cp];
        KVT[(size_t)(s * NC + cp) * 4096 + e0] = r;
        r += tv;
    }
}

// K6: final — MFMA: out = s2 * ( sq·KVp  +  maskedP·scomp · v ).
__global__ __launch_bounds__(256) void k_final(const float* __restrict__ Q,
                                               const float* __restrict__ V,
                                               const float* __restrict__ s2_g,
                                               const float* __restrict__ scomp_g,
                                               const float* __restrict__ Pg,
                                               const float* __restrict__ KVT,
                                               float* __restrict__ Out) {
    __shared__ __align__(16) unsigned short sqB[C * SB];    // [i][d]
    __shared__ __align__(16) unsigned short kvB[C * SB];    // [m][d] = KVT rows
    __shared__ __align__(16) unsigned short stB[C * SB];    // [i][j] masked P*scomp
    __shared__ __align__(16) unsigned short vsT[C * SB];    // [m][j]
    __shared__ float lsc[C], s2l[C];
    int b = blockIdx.x, s = b / NC, c = b % NC;
    int n = s / Hh, h = s % Hh, t = threadIdx.x;

    if (t < 64) lsc[t] = scomp_g[s * Ll + c * C + t];
    else if (t < 128) s2l[t - 64] = s2_g[s * Ll + c * C + (t - 64)];
    __syncthreads();

    // natural-row staging: sq, KVT, masked-P
#pragma unroll
    for (int j = 0; j < 4; j++) {
        int flat = 4 * t + 1024 * j, i = flat >> 6, d0 = flat & 63;
        float4 q4 = *(const float4*)&Q[gidx(n, c * C + i, h, d0)];
        float4 kv4 = *(const float4*)&KVT[(size_t)b * 4096 + flat];
        float4 p4 = *(const float4*)&Pg[(size_t)b * 4096 + flat];
        *(uint2*)&sqB[i * SB + d0] = make_uint2(pack2(sigf(q4.x), sigf(q4.y)),
                                                pack2(sigf(q4.z), sigf(q4.w)));
        *(uint2*)&kvB[i * SB + d0] = make_uint2(pack2(kv4.x, kv4.y), pack2(kv4.z, kv4.w));
        float m0v = (d0 + 0 <= i) ? fc(p4, 0) * lsc[d0 + 0] : 0.f;
        float m1v = (d0 + 1 <= i) ? fc(p4, 1) * lsc[d0 + 1] : 0.f;
        float m2v = (d0 + 2 <= i) ? fc(p4, 2) * lsc[d0 + 2] : 0.f;
        float m3v = (d0 + 3 <= i) ? fc(p4, 3) * lsc[d0 + 3] : 0.f;
        *(uint2*)&stB[i * SB + d0] = make_uint2(pack2(m0v, m1v), pack2(m2v, m3v));
    }
    // transposed staging of v (scomp NOT folded here; it's folded in stB)
    {
        int j0 = (t & 15) * 4, m0 = (((t >> 4) & 3) + 4 * (t >> 6)) * 4;
        float4 vr[4];
#pragma unroll
        for (int r = 0; r < 4; r++) vr[r] = *(const float4*)&V[gidx(n, c * C + j0 + r, h, m0)];
#pragma unroll
        for (int u = 0; u < 4; u++)
            *(uint2*)&vsT[(m0 + u) * SB + j0] = make_uint2(
                pack2(fc(vr[0], u), fc(vr[1], u)), pack2(fc(vr[2], u), fc(vr[3], u)));
    }
    __syncthreads();

    int w = t >> 6, lane = t & 63, m = lane & 15, q = lane >> 4;
    f32x4 acc[4] = {{0,0,0,0},{0,0,0,0},{0,0,0,0},{0,0,0,0}};
#pragma unroll
    for (int kk = 0; kk < 64; kk += 32) {   // mm1: sq · KVp   (contract d)
        short8 a = *(const short8*)&sqB[(16 * w + m) * SB + kk + q * 8];
#pragma unroll
        for (int J = 0; J < 4; J++) {
            short8 bb = *(const short8*)&kvB[(16 * J + m) * SB + kk + q * 8];
            acc[J] = MFMA16(a, bb, acc[J]);
        }
    }
#pragma unroll
    for (int kk = 0; kk < 64; kk += 32) {   // mm2: maskedP·scomp · v   (contract j)
        short8 a = *(const short8*)&stB[(16 * w + m) * SB + kk + q * 8];
#pragma unroll
        for (int J = 0; J < 4; J++) {
            short8 bb = *(const short8*)&vsT[(16 * J + m) * SB + kk + q * 8];
            acc[J] = MFMA16(a, bb, acc[J]);
        }
    }
#pragma unroll
    for (int J = 0; J < 4; J++)
#pragma unroll
        for (int r = 0; r < 4; r++) {
            int io = 16 * w + 4 * q + r;
            Out[gidx(n, c * C + io, h, 16 * J + m)] = acc[J][r] * s2l[io];
        }
}

extern "C" void kernel_launch(void* const* d_in, const int* in_sizes, int n_in,
                              void* d_out, int out_size, void* d_ws, size_t ws_size,
                              hipStream_t stream) {
    const float* Q = (const float*)d_in[0];
    const float* K = (const float*)d_in[1];
    const float* V = (const float*)d_in[2];
    float* Out = (float*)d_out;

    float* ws    = (float*)d_ws;
    float* SK    = ws;                  // SC*64
    float* SQ    = SK    + SC * 64;
    float* SKso  = SQ    + SC * 64;
    float* SQsi  = SKso  + SC * 64;
    float* si_g  = SQsi  + SC * 64;     // S*Ll each
    float* rw1_g = si_g  + S * Ll;
    float* rw2_g = rw1_g + S * Ll;
    float* s2_g  = rw2_g + S * Ll;
    float* e_g   = s2_g  + S * Ll;
    float* ecum_g= e_g   + S * Ll;
    float* scomp = ecum_g+ S * Ll;
    float* Tcs   = scomp + S * Ll;      // SC
    float* Pg    = Tcs   + SC;          // SC*4096
    float* KVT   = Pg    + (size_t)SC * 4096;

    k_sums<<<SC, 256, 0, stream>>>(Q, K, SK, SQ);
    k_pass1<<<SC, 256, 0, stream>>>(Q, K, SK, SQ, SKso, SQsi, si_g, rw1_g, rw2_g, Pg);
    k_pass2<<<SC, 256, 0, stream>>>(Q, K, SKso, SQsi, si_g, rw1_g, rw2_g, s2_g, e_g, ecum_g, Tcs);
    k_kv<<<SC, 256, 0, stream>>>(K, V, e_g, ecum_g, Tcs, scomp, KVT);
    k_prefixKV<<<256, 256, 0, stream>>>(KVT);
    k_final<<<SC, 256, 0, stream>>>(Q, V, s2_g, scomp, Pg, KVT, Out);
}